// Round 1
// 359.477 us; speedup vs baseline: 1.1660x; 1.1660x over previous
//
#include <hip/hip_runtime.h>

// WaterNetModel — R5: cache-resident chunk scan (NC=8, L=137), lane-per-
// hidden-unit parallelization, 8-deep P/T prefetch.
//
// R4 post-mortem: at L=8/NC=137 the pipeline moved ~548 MB in 419 us
// (1.3 TB/s effective vs 6.2 TB/s demonstrated by the harness fills) —
// latency-bound scans (1-deep prefetch, 16-wide per-thread state) plus
// ~200 MB of HBM intermediate traffic.
// R5: NC=8 makes all intermediates 3.1 MB (L2/L3-resident); thread =
// (site, hh, chunk) gives scalar per-lane state, low VGPR, and wave-
// contiguous 256 B stores in k_final; unroll-by-8 keeps 16 loads in
// flight per lane. Predicted dur_us ~100-140, k_final BW-bound.
//
// Recurrences per (site, hh):
//   snow:   s' = max(s + a, b), a = p_neg - melt_pot, b = p_neg
//           composition (A,B)∘(a,b) = (A+a, max(B+a,b))  (associative)
//   linear: h' = cl*(h + xin), cl = 1-gl  -> chunk: h_out = cl^L h_in + hpart
//
// buf0 = A -> hpart ; buf1 = B -> h0 ; buf2 = s0.

constexpr int NT = 1096;
constexpr int NS = 2048;
constexpr int NH = 16;
constexpr int NSH = NS * NH;          // 32768 = 2^15
constexpr int NC = 8;                 // chunks; NT = NC * L exactly
constexpr int L  = NT / NC;           // 137
static_assert(NC * L == NT, "NT must divide into NC chunks exactly");
constexpr int PF = 8;                 // prefetch depth (2*PF loads in flight)

__device__ __forceinline__ float sigm(float x) { return 1.0f / (1.0f + expf(-x)); }

// ---- K1: per-chunk snow composition (A,B), one (site,hh,chunk) per lane ----
__global__ __launch_bounds__(256) void k_scanA(
    const float* __restrict__ P, const float* __restrict__ T,
    const float* __restrict__ wsb,
    float* __restrict__ outA, float* __restrict__ outB)
{
    const int gid  = blockIdx.x * 256 + (int)threadIdx.x;   // 0 .. NC*NSH-1
    const int hh   = gid & (NH - 1);
    const int site = (gid >> 4) & (NS - 1);
    const int c    = gid >> 15;                              // NSH = 2^15

    const float mcv = expf(wsb[hh]) + 1.0f;
    const int t0 = c * L;

    float pf[PF], tf[PF];
    #pragma unroll
    for (int k = 0; k < PF; ++k) {
        pf[k] = P[(t0 + k) * NS + site];
        tf[k] = T[(t0 + k) * NS + site];
    }

    float A = 0.0f, B = -1e38f;
    auto step = [&](float Pk, float Tk) {
        const float tpos = fmaxf(Tk, 0.0f);
        const float pn   = (Tk < 0.0f) ? Pk : 0.0f;
        const float at   = pn - tpos * mcv;
        A += at;
        B = fmaxf(B + at, pn);
    };

    int base = 0;
    for (; base + PF <= L; base += PF) {
        #pragma unroll
        for (int k = 0; k < PF; ++k) {
            const float Pk = pf[k], Tk = tf[k];
            int tn = t0 + base + k + PF;
            tn = min(tn, NT - 1);                 // clamp: last-chunk overrun
            pf[k] = P[tn * NS + site];
            tf[k] = T[tn * NS + site];
            step(Pk, Tk);
        }
    }
    #pragma unroll
    for (int k = 0; k < PF; ++k) {
        if (base + k < L) step(pf[k], tf[k]);
    }

    outA[gid] = A;                                 // contiguous per wave
    outB[gid] = B;
}

// ---- K2: resolve chunk-boundary snow states (A,B) -> s0 (tiny, cache-hot) ----
__global__ __launch_bounds__(256) void k_resolveS(
    const float* __restrict__ A, const float* __restrict__ B,
    float* __restrict__ S0)
{
    const int idx = blockIdx.x * 256 + (int)threadIdx.x;    // 0 .. NSH-1
    float a[NC], b[NC];
    #pragma unroll
    for (int c = 0; c < NC; ++c) {
        a[c] = A[c * NSH + idx];
        b[c] = B[c * NSH + idx];
    }
    float s = 0.0f;
    #pragma unroll
    for (int c = 0; c < NC; ++c) {
        S0[c * NSH + idx] = s;
        s = fmaxf(s + a[c], b[c]);
    }
}

// ---- K3: per-chunk h summary hpart (reads s0, writes hpart) ----
__global__ __launch_bounds__(256) void k_scanH(
    const float* __restrict__ P, const float* __restrict__ T,
    const float* __restrict__ wi, const float* __restrict__ wl,
    const float* __restrict__ wsb,
    const float* __restrict__ S0, float* __restrict__ HP)
{
    const int gid  = blockIdx.x * 256 + (int)threadIdx.x;
    const int hh   = gid & (NH - 1);
    const int site = (gid >> 4) & (NS - 1);
    const int c    = gid >> 15;

    const float mcv = expf(wsb[hh]) + 1.0f;
    const float giv = sigm(wi[hh]);
    const float clv = 1.0f - sigm(wl[hh]);

    float s  = S0[gid];
    float hp = 0.0f;

    const int t0 = c * L;
    float pf[PF], tf[PF];
    #pragma unroll
    for (int k = 0; k < PF; ++k) {
        pf[k] = P[(t0 + k) * NS + site];
        tf[k] = T[(t0 + k) * NS + site];
    }

    auto step = [&](float Pk, float Tk) {
        const float tpos = fmaxf(Tk, 0.0f);
        const float pnn  = (Tk < 0.0f) ? Pk : 0.0f;
        const float ppp  = (Tk > 0.0f) ? Pk : 0.0f;
        const float smv  = tpos * mcv;
        const float m    = fminf(smv, s);
        s = s - m + pnn;
        const float xin  = (ppp + m) * giv;
        hp = clv * (hp + xin);
    };

    int base = 0;
    for (; base + PF <= L; base += PF) {
        #pragma unroll
        for (int k = 0; k < PF; ++k) {
            const float Pk = pf[k], Tk = tf[k];
            int tn = t0 + base + k + PF;
            tn = min(tn, NT - 1);
            pf[k] = P[tn * NS + site];
            tf[k] = T[tn * NS + site];
            step(Pk, Tk);
        }
    }
    #pragma unroll
    for (int k = 0; k < PF; ++k) {
        if (base + k < L) step(pf[k], tf[k]);
    }

    HP[gid] = hp;
}

// ---- K4: resolve chunk-boundary h states: hpart -> h0 (tiny, cache-hot) ----
__global__ __launch_bounds__(256) void k_resolveH(
    const float* __restrict__ wl, const float* __restrict__ HP,
    float* __restrict__ H0)
{
    const int idx = blockIdx.x * 256 + (int)threadIdx.x;    // 0 .. NSH-1
    const float cl  = 1.0f - sigm(wl[idx & (NH - 1)]);
    const float clL = powf(cl, (float)L);
    float hp[NC];
    #pragma unroll
    for (int c = 0; c < NC; ++c) hp[c] = HP[c * NSH + idx];
    float h = 0.0f;
    #pragma unroll
    for (int c = 0; c < NC; ++c) {
        H0[c * NSH + idx] = h;
        h = clL * h + hp[c];
    }
}

// ---- K5: final recompute + write Q,H,S (scalar lanes, contiguous stores) ----
__global__ __launch_bounds__(256) void k_final(
    const float* __restrict__ P, const float* __restrict__ T,
    const float* __restrict__ wi, const float* __restrict__ wo,
    const float* __restrict__ wl, const float* __restrict__ wsb,
    const float* __restrict__ S0, const float* __restrict__ H0,
    float* __restrict__ Q, float* __restrict__ H, float* __restrict__ S)
{
    const int gid  = blockIdx.x * 256 + (int)threadIdx.x;
    const int hh   = gid & (NH - 1);
    const int site = (gid >> 4) & (NS - 1);
    const int c    = gid >> 15;
    const int lidx = gid & (NSH - 1);              // site*NH + hh

    const float mcv = expf(wsb[hh]) + 1.0f;
    const float giv = sigm(wi[hh]);
    const float glv = sigm(wl[hh]);
    float mx = -1e30f;
    #pragma unroll
    for (int j = 0; j < NH; ++j) mx = fmaxf(mx, wo[j]);
    float den = 0.0f;
    #pragma unroll
    for (int j = 0; j < NH; ++j) den += expf(wo[j] - mx);
    const float aw = expf(wo[hh] - mx) / den;

    float s = S0[gid];
    float h = H0[gid];

    const int t0 = c * L;
    float pf[PF], tf[PF];
    #pragma unroll
    for (int k = 0; k < PF; ++k) {
        pf[k] = P[(t0 + k) * NS + site];
        tf[k] = T[(t0 + k) * NS + site];
    }

    auto step = [&](float Pk, float Tk, int ta) {
        const float tpos = fmaxf(Tk, 0.0f);
        const float pnn  = (Tk < 0.0f) ? Pk : 0.0f;
        const float ppp  = (Tk > 0.0f) ? Pk : 0.0f;
        const float smv  = tpos * mcv;
        const float m    = fminf(smv, s);
        s = s - m + pnn;
        const float xin  = (ppp + m) * giv;
        const float q    = (xin + h) * glv;
        h = h - q + xin;
        float qa = q * aw;
        qa += __shfl_xor(qa, 1, 16);
        qa += __shfl_xor(qa, 2, 16);
        qa += __shfl_xor(qa, 4, 16);
        qa += __shfl_xor(qa, 8, 16);
        const int ofs = ta * NSH + lidx;           // wave writes 256 B runs
        S[ofs] = s;
        H[ofs] = h;
        if (hh == 0) Q[ta * NS + site] = qa;
    };

    int base = 0;
    for (; base + PF <= L; base += PF) {
        #pragma unroll
        for (int k = 0; k < PF; ++k) {
            const float Pk = pf[k], Tk = tf[k];
            int tn = t0 + base + k + PF;
            tn = min(tn, NT - 1);
            pf[k] = P[tn * NS + site];
            tf[k] = T[tn * NS + site];
            step(Pk, Tk, t0 + base + k);
        }
    }
    #pragma unroll
    for (int k = 0; k < PF; ++k) {
        if (base + k < L) step(pf[k], tf[k], t0 + base + k);
    }
}

// ---- fallback: monolithic sequential kernel (used only if ws too small) ----
__global__ __launch_bounds__(64) void waternet_seq(
    const float* __restrict__ P, const float* __restrict__ T,
    const float* __restrict__ w_i, const float* __restrict__ w_o,
    const float* __restrict__ w_l, const float* __restrict__ w_s,
    float* __restrict__ Q, float* __restrict__ H, float* __restrict__ S)
{
    const int gid = blockIdx.x * 64 + (int)threadIdx.x;
    const int hh = gid & (NH - 1);
    const int site = gid >> 4;
    const float melt_coef = expf(w_s[hh]) + 1.0f;
    const float gi = sigm(w_i[hh]);
    const float gl = sigm(w_l[hh]);
    float mx = -1e30f;
    for (int j = 0; j < NH; ++j) mx = fmaxf(mx, w_o[j]);
    float denom = 0.0f;
    for (int j = 0; j < NH; ++j) denom += expf(w_o[j] - mx);
    const float a = expf(w_o[hh] - mx) / denom;
    float s = 0.0f, h = 0.0f;
    for (int t = 0; t < NT; ++t) {
        const float Pk = P[t * NS + site];
        const float Tk = T[t * NS + site];
        const float sm = fmaxf(Tk, 0.0f) * melt_coef;
        const float m = fminf(sm, s);
        s = s - m + ((Tk < 0.0f) ? Pk : 0.0f);
        const float xin = (((Tk > 0.0f) ? Pk : 0.0f) + m) * gi;
        const float q = (xin + h) * gl;
        h = h - q + xin;
        const int ofs = t * NSH + gid;
        S[ofs] = s; H[ofs] = h;
        float qa = q * a;
        qa += __shfl_xor(qa, 1, 16);
        qa += __shfl_xor(qa, 2, 16);
        qa += __shfl_xor(qa, 4, 16);
        qa += __shfl_xor(qa, 8, 16);
        if (hh == 0) Q[t * NS + site] = qa;
    }
}

extern "C" void kernel_launch(void* const* d_in, const int* in_sizes, int n_in,
                              void* d_out, int out_size, void* d_ws, size_t ws_size,
                              hipStream_t stream) {
    const float* P   = (const float*)d_in[0];
    const float* T   = (const float*)d_in[1];
    const float* w_i = (const float*)d_in[2];
    const float* w_o = (const float*)d_in[3];
    const float* w_l = (const float*)d_in[4];
    const float* w_s = (const float*)d_in[5];

    float* Q = (float*)d_out;
    float* H = Q + (size_t)NT * NS;
    float* S = H + (size_t)NT * NS * NH;

    const size_t need = 3ull * NC * NSH * sizeof(float);   // 3.1 MB
    if (ws_size < need) {
        waternet_seq<<<(NS * NH) / 64, 64, 0, stream>>>(P, T, w_i, w_o, w_l, w_s, Q, H, S);
        return;
    }

    float* buf0 = (float*)d_ws;                 // A, then hpart
    float* buf1 = buf0 + (size_t)NC * NSH;      // B, then h0
    float* buf2 = buf1 + (size_t)NC * NSH;      // s0

    const int nblk = (NC * NSH) / 256;          // 1024 blocks, 4 waves/SIMD
    const int rblk = NSH / 256;                 // 128 blocks

    k_scanA   <<<nblk, 256, 0, stream>>>(P, T, w_s, buf0, buf1);
    k_resolveS<<<rblk, 256, 0, stream>>>(buf0, buf1, buf2);
    k_scanH   <<<nblk, 256, 0, stream>>>(P, T, w_i, w_l, w_s, buf2, buf0);
    k_resolveH<<<rblk, 256, 0, stream>>>(w_l, buf0, buf1);
    k_final   <<<nblk, 256, 0, stream>>>(P, T, w_i, w_o, w_l, w_s, buf2, buf1,
                                         Q, H, S);
}